// Round 16
// baseline (401.162 us; speedup 1.0000x reference)
//
#include <hip/hip_runtime.h>

#define NN      100000
#define NUSERS  50000
#define NE      1250000
#define DIM     64
#define BN_EPS  1e-5f
#define NBUCK   8       // one bucket per XCD: scatter window 2MB csr + 50KB cursor L2-resident
#define NCHUNK  256     // blocks per bucket (grid 2048)
#define SLOT    40      // fixed CSR slots per node (max expected degree ~30)
#define CPAD    8       // cursor stride in ints (32B)

typedef __attribute__((ext_vector_type(8))) short s16x8;
typedef __attribute__((ext_vector_type(4))) float f32x4;

__device__ __forceinline__ short f2b(float f) {  // fp32 -> bf16 RNE
    unsigned u = __builtin_bit_cast(unsigned, f);
    u = (u + 0x7fffu + ((u >> 16) & 1u)) >> 16;
    return (short)u;
}
__device__ __forceinline__ float b2f(unsigned short s) {
    unsigned u = ((unsigned)s) << 16;
    return __builtin_bit_cast(float, u);
}

// ---------------------------------------------------------------------------
// Bucketed slot-CSR placement. r15 change: NT LOADS on the ei stream only.
// Theory (counter-backed): WRITE 57MB vs ~22MB dirty = mid-kernel eviction
// churn from the 10MB ei stream flowing through the same L2 that holds the
// bucket's 2MB csr window. nt loads keep the stream out of L2 (r0 evidence:
// nt-load variant had WRITE 50.0 vs 57.3). FETCH 40.8 = full 8x raw re-read,
// so L3 wasn't serving these loads anyway — nothing lost on the read side.
// (r9 lesson was nt STORES on scatter = bad; loads are the opposite case.)
__global__ __launch_bounds__(256) void place_part(const int* __restrict__ ei,
                                                  int* __restrict__ cursor,
                                                  int* __restrict__ csr_src) {
    int lane = threadIdx.x & 63, wave = threadIdx.x >> 6;
    int B = blockIdx.x & (NBUCK - 1);
    int gw = (blockIdx.x >> 3) * 4 + wave;
    const int NW = NCHUNK * 4;
    int gwr = gw + B * (NW / NBUCK);
    if (gwr >= NW) gwr -= NW;
    const int per = (NE + NW - 1) / NW;
    int e0 = gwr * per;
    int e1 = e0 + per; if (e1 > NE) e1 = NE;
    for (int eb = e0; eb < e1; eb += 8 * 64) {
        int d[8], s[8];
        bool k[8];
#pragma unroll
        for (int u = 0; u < 8; ++u) {
            int ee = eb + u * 64 + lane;
            bool in = ee < e1;
            int idx = in ? ee : e0;
            d[u] = __builtin_nontemporal_load(&ei[NE + idx]);
            s[u] = __builtin_nontemporal_load(&ei[idx]);
            k[u] = in && ((d[u] / 12500) == B);
        }
#pragma unroll
        for (int u = 0; u < 8; ++u) {
            if (k[u]) {
                int pos = atomicAdd(&cursor[d[u] * CPAD], 1);
                if (pos < SLOT) csr_src[d[u] * SLOT + pos] = s[u];
            }
        }
    }
}

// dinv[v] = rsqrt(deg[v]+1); threads <128 also compute the c0 bias-fold table
__global__ __launch_bounds__(256) void dinv_c0(const int* __restrict__ cursor,
                                               float* __restrict__ dinv,
                                               const float* __restrict__ Ws,
                                               const float* __restrict__ bs,
                                               float* __restrict__ c0) {
    int v = blockIdx.x * blockDim.x + threadIdx.x;
    if (v < NN) dinv[v] = rsqrtf((float)cursor[v * CPAD] + 1.0f);
    if (v < 128) {
        int l = v >> 6, j = v & 63;
        const float* Wl = Ws + (size_t)(l + 1) * 4096;
        const float* bl = bs + l * 64;
        float s = 0.0f;
        for (int k = 0; k < 64; ++k) s += bl[k] * Wl[j * 64 + k];
        c0[v] = s;
    }
}

// ---------------------------------------------------------------------------
// Layer-0 bf16 MFMA transform (r13 LDS-staged-W version, unchanged).
__global__ __launch_bounds__(256) void gemm_l0(const float* __restrict__ Xin,
                                               const float* __restrict__ W,
                                               const float* __restrict__ dinv,
                                               unsigned short* __restrict__ Gb) {
    __shared__ s16x8 WL[8][64];   // [t*2+c][lane], 8KB
    int lane = threadIdx.x & 63;
    int n16 = lane & 15, quad = lane >> 4;

#pragma unroll
    for (int e = threadIdx.x; e < 512; e += 256) {
        int ln = e & 63, tc = e >> 6;
        int tt = tc >> 1, cc = tc & 1;
        int m16 = ln & 15, qq = ln >> 4;
        const float4* wp = (const float4*)(W + (tt * 16 + m16) * 64 + cc * 32 + qq * 8);
        float4 w0 = wp[0], w1 = wp[1];
        s16x8 f;
        f[0] = f2b(w0.x); f[1] = f2b(w0.y); f[2] = f2b(w0.z); f[3] = f2b(w0.w);
        f[4] = f2b(w1.x); f[5] = f2b(w1.y); f[6] = f2b(w1.z); f[7] = f2b(w1.w);
        WL[tc][ln] = f;
    }
    __syncthreads();

    s16x8 bfrag[4][2];
#pragma unroll
    for (int t = 0; t < 4; ++t)
#pragma unroll
        for (int c = 0; c < 2; ++c)
            bfrag[t][c] = WL[t * 2 + c][lane];

    int wid = (blockIdx.x * blockDim.x + threadIdx.x) >> 6;
    int nw  = (gridDim.x * blockDim.x) >> 6;
    for (int tile = wid; tile < NN / 16; tile += nw) {
        int r0 = tile * 16;
        int m  = r0 + n16;
        s16x8 a[2];
#pragma unroll
        for (int c = 0; c < 2; ++c) {
            const float4* xp = (const float4*)(Xin + (size_t)m * 64 + c * 32 + quad * 8);
            float4 x0 = xp[0], x1 = xp[1];
            s16x8 f;
            f[0] = f2b(x0.x); f[1] = f2b(x0.y); f[2] = f2b(x0.z); f[3] = f2b(x0.w);
            f[4] = f2b(x1.x); f[5] = f2b(x1.y); f[6] = f2b(x1.z); f[7] = f2b(x1.w);
            a[c] = f;
        }
        f32x4 acc[4] = {{0,0,0,0},{0,0,0,0},{0,0,0,0},{0,0,0,0}};
#pragma unroll
        for (int c = 0; c < 2; ++c)
#pragma unroll
            for (int t = 0; t < 4; ++t)
                acc[t] = __builtin_amdgcn_mfma_f32_16x16x32_bf16(a[c], bfrag[t][c], acc[t], 0, 0, 0);

        float dvr[4];
#pragma unroll
        for (int r = 0; r < 4; ++r) dvr[r] = dinv[r0 + quad * 4 + r];
#pragma unroll
        for (int t = 0; t < 4; ++t)
#pragma unroll
            for (int r = 0; r < 4; ++r)
                Gb[(size_t)(r0 + quad * 4 + r) * 64 + t * 16 + n16] =
                    (unsigned short)f2b(dvr[r] * acc[t][r]);
    }
}

// ---------------------------------------------------------------------------
// 8-neighbor accumulation batch for one 16-lane group (unchanged).
template <int BASE>
__device__ __forceinline__ void gbatch8(const unsigned short* __restrict__ Gb,
                                        int v, int c, int g, int n, int ir,
                                        float& ax, float& ay, float& az, float& aw) {
    ushort4 val[8];
    float msk[8];
#pragma unroll
    for (int u = 0; u < 8; ++u) {
        int j = BASE + u;
        int s = __shfl(ir, g * 16 + (j & 15), 64);
        bool ok = j < n;
        msk[u] = ok ? 1.0f : 0.0f;
        val[u] = *(const ushort4*)(Gb + (size_t)(ok ? s : v) * 64 + c * 4);
    }
#pragma unroll
    for (int u = 0; u < 8; ++u) {
        ax = fmaf(msk[u], b2f(val[u].x), ax);
        ay = fmaf(msk[u], b2f(val[u].y), ay);
        az = fmaf(msk[u], b2f(val[u].z), az);
        aw = fmaf(msk[u], b2f(val[u].w), aw);
    }
}

// ---------------------------------------------------------------------------
// Fused gather. Block = 4 waves x 4 rows = one 16-row MFMA tile.
// FUSE=1: + next-layer transform in wave 0 (r15, verified -14us).
// FUSE=0 (last layer, r16): computes y = dv*acc + blast in f32, writes bf16 y
// to ACCb (bn_apply needs no dv/blast), and block-reduces sum(y), sum(y^2)
// via shfl (across the wave's 4 groups) + LDS (across 4 waves) + 128 global
// atomicAdds/block — deletes the bn_stats dispatch and its 12.8MB re-read.
// Atomic rate: 6250 adds/address spread over the kernel's ~55us = 1 per
// 8.8ns/address, well under memory-side atomic throughput.
template <int FUSE>
__global__ __launch_bounds__(256) void gather_fused(const int* __restrict__ cursor,
                                                    const int* __restrict__ csr_src,
                                                    const unsigned short* __restrict__ Gb_in,
                                                    const float* __restrict__ W,
                                                    const float* __restrict__ dinv,
                                                    const float* __restrict__ c0,   // FUSE=0: blast
                                                    unsigned short* __restrict__ outp,
                                                    float* __restrict__ sums) {
    __shared__ s16x8 WL[8][64];    // next-layer W frags, 8KB (FUSE only)
    __shared__ float AT[16][68];   // FUSE=1: aggregated tile; FUSE=0: reuse as WS
    int lane = threadIdx.x & 63, wave = threadIdx.x >> 6;
    int c = lane & 15, g = lane >> 4;

    if (FUSE) {
#pragma unroll
        for (int e = threadIdx.x; e < 512; e += 256) {
            int ln = e & 63, tc = e >> 6;
            int tt = tc >> 1, cc2 = tc & 1;
            int m16 = ln & 15, qq = ln >> 4;
            const float4* wp = (const float4*)(W + (tt * 16 + m16) * 64 + cc2 * 32 + qq * 8);
            float4 w0 = wp[0], w1 = wp[1];
            s16x8 f;
            f[0] = f2b(w0.x); f[1] = f2b(w0.y); f[2] = f2b(w0.z); f[3] = f2b(w0.w);
            f[4] = f2b(w1.x); f[5] = f2b(w1.y); f[6] = f2b(w1.z); f[7] = f2b(w1.w);
            WL[tc][ln] = f;
        }
    }

    int r0 = blockIdx.x * 16;              // NN/16 = 6250 blocks exactly
    int v  = r0 + wave * 4 + g;
    int n = cursor[v * CPAD]; if (n > SLOT) n = SLOT;
    int i0 = csr_src[v * SLOT + c];
    ushort4 sv = *(const ushort4*)(Gb_in + (size_t)v * 64 + c * 4);
    float ax = b2f(sv.x), ay = b2f(sv.y), az = b2f(sv.z), aw = b2f(sv.w);
    if (n > 0)  gbatch8<0 >(Gb_in, v, c, g, n, i0, ax, ay, az, aw);
    if (n > 8)  gbatch8<8 >(Gb_in, v, c, g, n, i0, ax, ay, az, aw);
    if (n > 16) {
        int i1 = csr_src[v * SLOT + 16 + c];
        gbatch8<16>(Gb_in, v, c, g, n, i1, ax, ay, az, aw);
        if (n > 24) gbatch8<24>(Gb_in, v, c, g, n, i1, ax, ay, az, aw);
        if (n > 32) {
            int i2 = csr_src[v * SLOT + 32 + (c & 7)];
            gbatch8<32>(Gb_in, v, c, g, n, i2, ax, ay, az, aw);
        }
    }

    if (!FUSE) {
        // y = dv*acc + b; write bf16 y; block-reduce stats
        float dv = dinv[v];
        float y0 = dv * ax + c0[c * 4 + 0];
        float y1 = dv * ay + c0[c * 4 + 1];
        float y2 = dv * az + c0[c * 4 + 2];
        float y3 = dv * aw + c0[c * 4 + 3];
        ushort4 o;
        o.x = (unsigned short)f2b(y0); o.y = (unsigned short)f2b(y1);
        o.z = (unsigned short)f2b(y2); o.w = (unsigned short)f2b(y3);
        *(ushort4*)(outp + (size_t)v * 64 + c * 4) = o;
        // sum across the wave's 4 rows (groups): xor16 + xor32 on same-c lanes
        float s0 = y0, s1 = y1, s2 = y2, s3 = y3;
        float q0 = y0 * y0, q1 = y1 * y1, q2 = y2 * y2, q3 = y3 * y3;
#pragma unroll
        for (int off = 16; off < 64; off <<= 1) {
            s0 += __shfl_xor(s0, off, 64); s1 += __shfl_xor(s1, off, 64);
            s2 += __shfl_xor(s2, off, 64); s3 += __shfl_xor(s3, off, 64);
            q0 += __shfl_xor(q0, off, 64); q1 += __shfl_xor(q1, off, 64);
            q2 += __shfl_xor(q2, off, 64); q3 += __shfl_xor(q3, off, 64);
        }
        if (g == 0) {   // lane<16 holds per-wave col sums for cols c*4..c*4+3
            *(float4*)&AT[wave * 2][c * 4]     = make_float4(s0, s1, s2, s3);
            *(float4*)&AT[wave * 2 + 1][c * 4] = make_float4(q0, q1, q2, q3);
        }
        __syncthreads();
        if (threadIdx.x < 128) {   // j = tid&63, kind = tid>>6 (0=sum,1=sumsq)
            int j = threadIdx.x & 63, kind = threadIdx.x >> 6;
            float t = AT[0 + kind][j] + AT[2 + kind][j] + AT[4 + kind][j] + AT[6 + kind][j];
            atomicAdd(&sums[kind * 64 + j], t);
        }
        return;
    }

    float4 f4; f4.x = ax; f4.y = ay; f4.z = az; f4.w = aw;
    *(float4*)&AT[wave * 4 + g][c * 4] = f4;   // 272B row stride, 16B aligned
    __syncthreads();
    if (wave != 0) return;

    // --- wave 0: transform the 16-row tile (next layer) ---
    int n16 = lane & 15, quad = lane >> 4;
    s16x8 a[2];
#pragma unroll
    for (int cc2 = 0; cc2 < 2; ++cc2) {
        const float* ap = &AT[n16][cc2 * 32 + quad * 8];
        s16x8 f;
#pragma unroll
        for (int q2 = 0; q2 < 8; ++q2) f[q2] = f2b(ap[q2]);
        a[cc2] = f;
    }
    s16x8 bfrag[4][2];
#pragma unroll
    for (int t = 0; t < 4; ++t)
#pragma unroll
        for (int cc2 = 0; cc2 < 2; ++cc2)
            bfrag[t][cc2] = WL[t * 2 + cc2][lane];

    f32x4 acc[4] = {{0,0,0,0},{0,0,0,0},{0,0,0,0},{0,0,0,0}};
#pragma unroll
    for (int cc2 = 0; cc2 < 2; ++cc2)
#pragma unroll
        for (int t = 0; t < 4; ++t)
            acc[t] = __builtin_amdgcn_mfma_f32_16x16x32_bf16(a[cc2], bfrag[t][cc2], acc[t], 0, 0, 0);

    float dvr[4];
#pragma unroll
    for (int r = 0; r < 4; ++r) dvr[r] = dinv[r0 + quad * 4 + r];
#pragma unroll
    for (int t = 0; t < 4; ++t) {
        float cc2 = c0[t * 16 + n16];
#pragma unroll
        for (int r = 0; r < 4; ++r) {
            float dv = dvr[r];
            float g2 = dv * dv * acc[t][r] + dv * cc2;
            outp[(size_t)(r0 + quad * 4 + r) * 64 + t * 16 + n16] = (unsigned short)f2b(g2);
        }
    }
}

// ---------------------------------------------------------------------------
// bn_apply: ACCb now holds y (bf16) directly — no dv/blast needed.
__global__ __launch_bounds__(256) void bn_apply(const unsigned short* __restrict__ ACCb,
                                                const float* __restrict__ sums,
                                                const float* __restrict__ gamma,
                                                const float* __restrict__ beta,
                                                float* __restrict__ out) {
    const float invN = 1.0f / (float)NN;
    int stride = gridDim.x * blockDim.x;
    for (int i = blockIdx.x * blockDim.x + threadIdx.x; i < NN * 64; i += stride) {
        int j = i & 63;
        float mean = sums[j] * invN;
        float var  = sums[64 + j] * invN - mean * mean;
        float y = b2f(ACCb[i]);
        out[i] = (y - mean) * rsqrtf(var + BN_EPS) * gamma[j] + beta[j];
    }
}

// ---------------------------------------------------------------------------
extern "C" void kernel_launch(void* const* d_in, const int* in_sizes, int n_in,
                              void* d_out, int out_size, void* d_ws, size_t ws_size,
                              hipStream_t stream) {
    const float* x     = (const float*)d_in[0];
    const int*   ei    = (const int*)d_in[1];
    const float* Ws    = (const float*)d_in[2];
    const float* bs    = (const float*)d_in[3];
    const float* gamma = (const float*)d_in[4];
    const float* beta  = (const float*)d_in[5];
    float* out = (float*)d_out;

    char* ws = (char*)d_ws;
    size_t off = 0;
    unsigned short* ACCb = (unsigned short*)(ws + off); off += (size_t)NN * 64 * 2;
    unsigned short* GbA  = (unsigned short*)(ws + off); off += (size_t)NN * 64 * 2;
    unsigned short* GbB  = (unsigned short*)(ws + off); off += (size_t)NN * 64 * 2;
    float* dinv    = (float*)(ws + off); off += (size_t)NN * 4;
    float* sums    = (float*)(ws + off); off += 128 * 4;
    float* c0      = (float*)(ws + off); off += 128 * 4;
    int*   cursor  = (int*)(ws + off);   off += (size_t)NN * CPAD * 4;
    int*   csr_src = (int*)(ws + off);   off += (size_t)NN * SLOT * 4;

    hipMemsetAsync(cursor, 0, (size_t)NN * CPAD * sizeof(int), stream);
    hipMemsetAsync(sums, 0, 128 * sizeof(float), stream);

    // --- slot-CSR build: bucketed, nt ei loads ---
    place_part<<<NBUCK * NCHUNK, 256, 0, stream>>>(ei, cursor, csr_src);
    dinv_c0<<<(NN + 255) / 256, 256, 0, stream>>>(cursor, dinv, Ws, bs, c0);

    // --- 3 GCN layers: L0 transform, fused gather+transform, last gather+BN-stats ---
    gemm_l0<<<1563, 256, 0, stream>>>(x, Ws, dinv, GbA);
    gather_fused<1><<<6250, 256, 0, stream>>>(cursor, csr_src, GbA,
                                              Ws + 4096, dinv, c0, GbB, nullptr);
    gather_fused<1><<<6250, 256, 0, stream>>>(cursor, csr_src, GbB,
                                              Ws + 8192, dinv, c0 + 64, GbA, nullptr);
    gather_fused<0><<<6250, 256, 0, stream>>>(cursor, csr_src, GbA,
                                              nullptr, dinv, bs + 128, ACCb, sums);

    // --- BatchNorm apply (stats fused into last gather) ---
    bn_apply<<<2048, 256, 0, stream>>>(ACCb, sums, gamma, beta, out);
}

// Round 17
// 323.293 us; speedup vs baseline: 1.2409x; 1.2409x over previous
//
#include <hip/hip_runtime.h>

#define NN      100000
#define NUSERS  50000
#define NE      1250000
#define DIM     64
#define BN_EPS  1e-5f
#define NBUCK   8
#define NCHUNK  256
#define SLOT    40
#define CPAD    8

typedef __attribute__((ext_vector_type(8))) short s16x8;
typedef __attribute__((ext_vector_type(4))) float f32x4;

__device__ __forceinline__ short f2b(float f) {  // fp32 -> bf16 RNE
    unsigned u = __builtin_bit_cast(unsigned, f);
    u = (u + 0x7fffu + ((u >> 16) & 1u)) >> 16;
    return (short)u;
}
__device__ __forceinline__ float b2f(unsigned short s) {
    unsigned u = ((unsigned)s) << 16;
    return __builtin_bit_cast(float, u);
}

// ---------------------------------------------------------------------------
// Bucketed slot-CSR placement + nt ei loads (r16 change, kept for isolated
// attribution this round — r16's top-5 cutoff hid place_part).
// r16 lesson recorded: BN-stats fusion into gather = 800K atomics on 8 cache
// lines = serialized RMW, +100us. REVERTED here.
__global__ __launch_bounds__(256) void place_part(const int* __restrict__ ei,
                                                  int* __restrict__ cursor,
                                                  int* __restrict__ csr_src) {
    int lane = threadIdx.x & 63, wave = threadIdx.x >> 6;
    int B = blockIdx.x & (NBUCK - 1);
    int gw = (blockIdx.x >> 3) * 4 + wave;
    const int NW = NCHUNK * 4;
    int gwr = gw + B * (NW / NBUCK);
    if (gwr >= NW) gwr -= NW;
    const int per = (NE + NW - 1) / NW;
    int e0 = gwr * per;
    int e1 = e0 + per; if (e1 > NE) e1 = NE;
    for (int eb = e0; eb < e1; eb += 8 * 64) {
        int d[8], s[8];
        bool k[8];
#pragma unroll
        for (int u = 0; u < 8; ++u) {
            int ee = eb + u * 64 + lane;
            bool in = ee < e1;
            int idx = in ? ee : e0;
            d[u] = __builtin_nontemporal_load(&ei[NE + idx]);
            s[u] = __builtin_nontemporal_load(&ei[idx]);
            k[u] = in && ((d[u] / 12500) == B);
        }
#pragma unroll
        for (int u = 0; u < 8; ++u) {
            if (k[u]) {
                int pos = atomicAdd(&cursor[d[u] * CPAD], 1);
                if (pos < SLOT) csr_src[d[u] * SLOT + pos] = s[u];
            }
        }
    }
}

// dinv[v] = rsqrt(deg[v]+1); threads <128 also compute the c0 bias-fold table
__global__ __launch_bounds__(256) void dinv_c0(const int* __restrict__ cursor,
                                               float* __restrict__ dinv,
                                               const float* __restrict__ Ws,
                                               const float* __restrict__ bs,
                                               float* __restrict__ c0) {
    int v = blockIdx.x * blockDim.x + threadIdx.x;
    if (v < NN) dinv[v] = rsqrtf((float)cursor[v * CPAD] + 1.0f);
    if (v < 128) {
        int l = v >> 6, j = v & 63;
        const float* Wl = Ws + (size_t)(l + 1) * 4096;
        const float* bl = bs + l * 64;
        float s = 0.0f;
        for (int k = 0; k < 64; ++k) s += bl[k] * Wl[j * 64 + k];
        c0[v] = s;
    }
}

// ---------------------------------------------------------------------------
// Layer-0 bf16 MFMA transform (r13 LDS-staged-W version, unchanged).
__global__ __launch_bounds__(256) void gemm_l0(const float* __restrict__ Xin,
                                               const float* __restrict__ W,
                                               const float* __restrict__ dinv,
                                               unsigned short* __restrict__ Gb) {
    __shared__ s16x8 WL[8][64];   // [t*2+c][lane], 8KB
    int lane = threadIdx.x & 63;
    int n16 = lane & 15, quad = lane >> 4;

#pragma unroll
    for (int e = threadIdx.x; e < 512; e += 256) {
        int ln = e & 63, tc = e >> 6;
        int tt = tc >> 1, cc = tc & 1;
        int m16 = ln & 15, qq = ln >> 4;
        const float4* wp = (const float4*)(W + (tt * 16 + m16) * 64 + cc * 32 + qq * 8);
        float4 w0 = wp[0], w1 = wp[1];
        s16x8 f;
        f[0] = f2b(w0.x); f[1] = f2b(w0.y); f[2] = f2b(w0.z); f[3] = f2b(w0.w);
        f[4] = f2b(w1.x); f[5] = f2b(w1.y); f[6] = f2b(w1.z); f[7] = f2b(w1.w);
        WL[tc][ln] = f;
    }
    __syncthreads();

    s16x8 bfrag[4][2];
#pragma unroll
    for (int t = 0; t < 4; ++t)
#pragma unroll
        for (int c = 0; c < 2; ++c)
            bfrag[t][c] = WL[t * 2 + c][lane];

    int wid = (blockIdx.x * blockDim.x + threadIdx.x) >> 6;
    int nw  = (gridDim.x * blockDim.x) >> 6;
    for (int tile = wid; tile < NN / 16; tile += nw) {
        int r0 = tile * 16;
        int m  = r0 + n16;
        s16x8 a[2];
#pragma unroll
        for (int c = 0; c < 2; ++c) {
            const float4* xp = (const float4*)(Xin + (size_t)m * 64 + c * 32 + quad * 8);
            float4 x0 = xp[0], x1 = xp[1];
            s16x8 f;
            f[0] = f2b(x0.x); f[1] = f2b(x0.y); f[2] = f2b(x0.z); f[3] = f2b(x0.w);
            f[4] = f2b(x1.x); f[5] = f2b(x1.y); f[6] = f2b(x1.z); f[7] = f2b(x1.w);
            a[c] = f;
        }
        f32x4 acc[4] = {{0,0,0,0},{0,0,0,0},{0,0,0,0},{0,0,0,0}};
#pragma unroll
        for (int c = 0; c < 2; ++c)
#pragma unroll
            for (int t = 0; t < 4; ++t)
                acc[t] = __builtin_amdgcn_mfma_f32_16x16x32_bf16(a[c], bfrag[t][c], acc[t], 0, 0, 0);

        float dvr[4];
#pragma unroll
        for (int r = 0; r < 4; ++r) dvr[r] = dinv[r0 + quad * 4 + r];
#pragma unroll
        for (int t = 0; t < 4; ++t)
#pragma unroll
            for (int r = 0; r < 4; ++r)
                Gb[(size_t)(r0 + quad * 4 + r) * 64 + t * 16 + n16] =
                    (unsigned short)f2b(dvr[r] * acc[t][r]);
    }
}

// ---------------------------------------------------------------------------
// 8-neighbor accumulation batch for one 16-lane group (unchanged).
template <int BASE>
__device__ __forceinline__ void gbatch8(const unsigned short* __restrict__ Gb,
                                        int v, int c, int g, int n, int ir,
                                        float& ax, float& ay, float& az, float& aw) {
    ushort4 val[8];
    float msk[8];
#pragma unroll
    for (int u = 0; u < 8; ++u) {
        int j = BASE + u;
        int s = __shfl(ir, g * 16 + (j & 15), 64);
        bool ok = j < n;
        msk[u] = ok ? 1.0f : 0.0f;
        val[u] = *(const ushort4*)(Gb + (size_t)(ok ? s : v) * 64 + c * 4);
    }
#pragma unroll
    for (int u = 0; u < 8; ++u) {
        ax = fmaf(msk[u], b2f(val[u].x), ax);
        ay = fmaf(msk[u], b2f(val[u].y), ay);
        az = fmaf(msk[u], b2f(val[u].z), az);
        aw = fmaf(msk[u], b2f(val[u].w), aw);
    }
}

// ---------------------------------------------------------------------------
// Fused gather (r15 verified version). Block = 4 waves x 4 rows = one tile.
// FUSE=1: next-layer transform in wave 0 (-14us verified r15).
// FUSE=0: plain gather, writes bf16 acc for BN (r16's stats fusion REVERTED:
// 800K atomics on 8 lines serialized, +100us).
template <int FUSE>
__global__ __launch_bounds__(256) void gather_fused(const int* __restrict__ cursor,
                                                    const int* __restrict__ csr_src,
                                                    const unsigned short* __restrict__ Gb_in,
                                                    const float* __restrict__ W,
                                                    const float* __restrict__ dinv,
                                                    const float* __restrict__ c0,
                                                    unsigned short* __restrict__ outp) {
    __shared__ s16x8 WL[8][64];    // next-layer W frags, 8KB (FUSE only)
    __shared__ float AT[16][68];   // aggregated tile, f32, +4 pad
    int lane = threadIdx.x & 63, wave = threadIdx.x >> 6;
    int c = lane & 15, g = lane >> 4;

    if (FUSE) {
#pragma unroll
        for (int e = threadIdx.x; e < 512; e += 256) {
            int ln = e & 63, tc = e >> 6;
            int tt = tc >> 1, cc2 = tc & 1;
            int m16 = ln & 15, qq = ln >> 4;
            const float4* wp = (const float4*)(W + (tt * 16 + m16) * 64 + cc2 * 32 + qq * 8);
            float4 w0 = wp[0], w1 = wp[1];
            s16x8 f;
            f[0] = f2b(w0.x); f[1] = f2b(w0.y); f[2] = f2b(w0.z); f[3] = f2b(w0.w);
            f[4] = f2b(w1.x); f[5] = f2b(w1.y); f[6] = f2b(w1.z); f[7] = f2b(w1.w);
            WL[tc][ln] = f;
        }
    }

    int r0 = blockIdx.x * 16;              // NN/16 = 6250 blocks exactly
    int v  = r0 + wave * 4 + g;
    int n = cursor[v * CPAD]; if (n > SLOT) n = SLOT;
    int i0 = csr_src[v * SLOT + c];
    ushort4 sv = *(const ushort4*)(Gb_in + (size_t)v * 64 + c * 4);
    float ax = b2f(sv.x), ay = b2f(sv.y), az = b2f(sv.z), aw = b2f(sv.w);
    if (n > 0)  gbatch8<0 >(Gb_in, v, c, g, n, i0, ax, ay, az, aw);
    if (n > 8)  gbatch8<8 >(Gb_in, v, c, g, n, i0, ax, ay, az, aw);
    if (n > 16) {
        int i1 = csr_src[v * SLOT + 16 + c];
        gbatch8<16>(Gb_in, v, c, g, n, i1, ax, ay, az, aw);
        if (n > 24) gbatch8<24>(Gb_in, v, c, g, n, i1, ax, ay, az, aw);
        if (n > 32) {
            int i2 = csr_src[v * SLOT + 32 + (c & 7)];
            gbatch8<32>(Gb_in, v, c, g, n, i2, ax, ay, az, aw);
        }
    }

    if (!FUSE) {
        ushort4 o;
        o.x = (unsigned short)f2b(ax); o.y = (unsigned short)f2b(ay);
        o.z = (unsigned short)f2b(az); o.w = (unsigned short)f2b(aw);
        *(ushort4*)(outp + (size_t)v * 64 + c * 4) = o;
        return;
    }

    float4 f4; f4.x = ax; f4.y = ay; f4.z = az; f4.w = aw;
    *(float4*)&AT[wave * 4 + g][c * 4] = f4;
    __syncthreads();
    if (wave != 0) return;

    // --- wave 0: transform the 16-row tile (next layer) ---
    int n16 = lane & 15, quad = lane >> 4;
    s16x8 a[2];
#pragma unroll
    for (int cc2 = 0; cc2 < 2; ++cc2) {
        const float* ap = &AT[n16][cc2 * 32 + quad * 8];
        s16x8 f;
#pragma unroll
        for (int q2 = 0; q2 < 8; ++q2) f[q2] = f2b(ap[q2]);
        a[cc2] = f;
    }
    s16x8 bfrag[4][2];
#pragma unroll
    for (int t = 0; t < 4; ++t)
#pragma unroll
        for (int cc2 = 0; cc2 < 2; ++cc2)
            bfrag[t][cc2] = WL[t * 2 + cc2][lane];

    f32x4 acc[4] = {{0,0,0,0},{0,0,0,0},{0,0,0,0},{0,0,0,0}};
#pragma unroll
    for (int cc2 = 0; cc2 < 2; ++cc2)
#pragma unroll
        for (int t = 0; t < 4; ++t)
            acc[t] = __builtin_amdgcn_mfma_f32_16x16x32_bf16(a[cc2], bfrag[t][cc2], acc[t], 0, 0, 0);

    float dvr[4];
#pragma unroll
    for (int r = 0; r < 4; ++r) dvr[r] = dinv[r0 + quad * 4 + r];
#pragma unroll
    for (int t = 0; t < 4; ++t) {
        float cc2 = c0[t * 16 + n16];
#pragma unroll
        for (int r = 0; r < 4; ++r) {
            float dv = dvr[r];
            float g2 = dv * dv * acc[t][r] + dv * cc2;
            outp[(size_t)(r0 + quad * 4 + r) * 64 + t * 16 + n16] = (unsigned short)f2b(g2);
        }
    }
}

// ---------------------------------------------------------------------------
__global__ __launch_bounds__(256) void bn_stats(const unsigned short* __restrict__ ACCb,
                                                const float* __restrict__ dinv,
                                                const float* __restrict__ blast,
                                                float* __restrict__ sums) {
    int j = threadIdx.x & 63;
    float b = blast[j];
    int wid = (blockIdx.x * blockDim.x + threadIdx.x) >> 6;
    int nw  = (gridDim.x * blockDim.x) >> 6;
    float s = 0.0f, s2 = 0.0f;
    for (int v = wid; v < NN; v += nw) {
        float y = dinv[v] * b2f(ACCb[(size_t)v * 64 + j]) + b;
        s += y;
        s2 += y * y;
    }
    __shared__ float ls[256], ls2[256];
    ls[threadIdx.x] = s;
    ls2[threadIdx.x] = s2;
    __syncthreads();
    if (threadIdx.x < 64) {
        s  = ls[threadIdx.x] + ls[threadIdx.x + 64] + ls[threadIdx.x + 128] + ls[threadIdx.x + 192];
        s2 = ls2[threadIdx.x] + ls2[threadIdx.x + 64] + ls2[threadIdx.x + 128] + ls2[threadIdx.x + 192];
        atomicAdd(&sums[j], s);
        atomicAdd(&sums[64 + j], s2);
    }
}

__global__ __launch_bounds__(256) void bn_apply(const unsigned short* __restrict__ ACCb,
                                                const float* __restrict__ dinv,
                                                const float* __restrict__ blast,
                                                const float* __restrict__ sums,
                                                const float* __restrict__ gamma,
                                                const float* __restrict__ beta,
                                                float* __restrict__ out) {
    const float invN = 1.0f / (float)NN;
    int stride = gridDim.x * blockDim.x;
    for (int i = blockIdx.x * blockDim.x + threadIdx.x; i < NN * 64; i += stride) {
        int j = i & 63;
        int v = i >> 6;
        float mean = sums[j] * invN;
        float var  = sums[64 + j] * invN - mean * mean;
        float y = dinv[v] * b2f(ACCb[i]) + blast[j];
        out[i] = (y - mean) * rsqrtf(var + BN_EPS) * gamma[j] + beta[j];
    }
}

// ---------------------------------------------------------------------------
extern "C" void kernel_launch(void* const* d_in, const int* in_sizes, int n_in,
                              void* d_out, int out_size, void* d_ws, size_t ws_size,
                              hipStream_t stream) {
    const float* x     = (const float*)d_in[0];
    const int*   ei    = (const int*)d_in[1];
    const float* Ws    = (const float*)d_in[2];
    const float* bs    = (const float*)d_in[3];
    const float* gamma = (const float*)d_in[4];
    const float* beta  = (const float*)d_in[5];
    float* out = (float*)d_out;

    char* ws = (char*)d_ws;
    size_t off = 0;
    unsigned short* ACCb = (unsigned short*)(ws + off); off += (size_t)NN * 64 * 2;
    unsigned short* GbA  = (unsigned short*)(ws + off); off += (size_t)NN * 64 * 2;
    unsigned short* GbB  = (unsigned short*)(ws + off); off += (size_t)NN * 64 * 2;
    float* dinv    = (float*)(ws + off); off += (size_t)NN * 4;
    float* sums    = (float*)(ws + off); off += 128 * 4;
    float* c0      = (float*)(ws + off); off += 128 * 4;
    int*   cursor  = (int*)(ws + off);   off += (size_t)NN * CPAD * 4;
    int*   csr_src = (int*)(ws + off);   off += (size_t)NN * SLOT * 4;

    hipMemsetAsync(cursor, 0, (size_t)NN * CPAD * sizeof(int), stream);
    hipMemsetAsync(sums, 0, 128 * sizeof(float), stream);

    // --- slot-CSR build: bucketed, nt ei loads ---
    place_part<<<NBUCK * NCHUNK, 256, 0, stream>>>(ei, cursor, csr_src);
    dinv_c0<<<(NN + 255) / 256, 256, 0, stream>>>(cursor, dinv, Ws, bs, c0);

    // --- 3 GCN layers: L0 transform, fused gather+transform, last plain ---
    gemm_l0<<<1563, 256, 0, stream>>>(x, Ws, dinv, GbA);
    gather_fused<1><<<6250, 256, 0, stream>>>(cursor, csr_src, GbA,
                                              Ws + 4096, dinv, c0, GbB);
    gather_fused<1><<<6250, 256, 0, stream>>>(cursor, csr_src, GbB,
                                              Ws + 8192, dinv, c0 + 64, GbA);
    gather_fused<0><<<6250, 256, 0, stream>>>(cursor, csr_src, GbA,
                                              nullptr, nullptr, nullptr, ACCb);

    // --- BatchNorm ---
    bn_stats<<<2048, 256, 0, stream>>>(ACCb, dinv, bs + 128, sums);
    bn_apply<<<2048, 256, 0, stream>>>(ACCb, dinv, bs + 128, sums, gamma, beta, out);
}

// Round 18
// 316.223 us; speedup vs baseline: 1.2686x; 1.0224x over previous
//
#include <hip/hip_runtime.h>

#define NN      100000
#define NUSERS  50000
#define NE      1250000
#define DIM     64
#define BN_EPS  1e-5f
#define NBUCK   8
#define NCHUNK  256
#define SLOT    40
#define CPAD    8

typedef __attribute__((ext_vector_type(8))) short s16x8;
typedef __attribute__((ext_vector_type(4))) float f32x4;

__device__ __forceinline__ short f2b(float f) {  // fp32 -> bf16 RNE
    unsigned u = __builtin_bit_cast(unsigned, f);
    u = (u + 0x7fffu + ((u >> 16) & 1u)) >> 16;
    return (short)u;
}
__device__ __forceinline__ float b2f(unsigned short s) {
    unsigned u = ((unsigned)s) << 16;
    return __builtin_bit_cast(float, u);
}

// ---------------------------------------------------------------------------
// Bucketed slot-CSR placement — PLAIN cached loads (r17 A/B: nt ei loads
// regressed 62->69us, FETCH 40.8->43.8MB: nt bypasses L3 retention, which the
// bucket-rotation re-read scheme depends on. nt refuted in BOTH directions on
// this kernel: stores r9, loads r17. Default caching is the optimum here.)
__global__ __launch_bounds__(256) void place_part(const int* __restrict__ ei,
                                                  int* __restrict__ cursor,
                                                  int* __restrict__ csr_src) {
    int lane = threadIdx.x & 63, wave = threadIdx.x >> 6;
    int B = blockIdx.x & (NBUCK - 1);
    int gw = (blockIdx.x >> 3) * 4 + wave;
    const int NW = NCHUNK * 4;
    int gwr = gw + B * (NW / NBUCK);
    if (gwr >= NW) gwr -= NW;
    const int per = (NE + NW - 1) / NW;
    int e0 = gwr * per;
    int e1 = e0 + per; if (e1 > NE) e1 = NE;
    for (int eb = e0; eb < e1; eb += 8 * 64) {
        int d[8], s[8];
        bool k[8];
#pragma unroll
        for (int u = 0; u < 8; ++u) {
            int ee = eb + u * 64 + lane;
            bool in = ee < e1;
            int idx = in ? ee : e0;
            d[u] = ei[NE + idx];
            s[u] = ei[idx];
            k[u] = in && ((d[u] / 12500) == B);
        }
#pragma unroll
        for (int u = 0; u < 8; ++u) {
            if (k[u]) {
                int pos = atomicAdd(&cursor[d[u] * CPAD], 1);
                if (pos < SLOT) csr_src[d[u] * SLOT + pos] = s[u];
            }
        }
    }
}

// dinv[v] = rsqrt(deg[v]+1); threads <128 also compute the c0 bias-fold table
__global__ __launch_bounds__(256) void dinv_c0(const int* __restrict__ cursor,
                                               float* __restrict__ dinv,
                                               const float* __restrict__ Ws,
                                               const float* __restrict__ bs,
                                               float* __restrict__ c0) {
    int v = blockIdx.x * blockDim.x + threadIdx.x;
    if (v < NN) dinv[v] = rsqrtf((float)cursor[v * CPAD] + 1.0f);
    if (v < 128) {
        int l = v >> 6, j = v & 63;
        const float* Wl = Ws + (size_t)(l + 1) * 4096;
        const float* bl = bs + l * 64;
        float s = 0.0f;
        for (int k = 0; k < 64; ++k) s += bl[k] * Wl[j * 64 + k];
        c0[v] = s;
    }
}

// ---------------------------------------------------------------------------
// Layer-0 bf16 MFMA transform (r13 LDS-staged-W version, unchanged).
__global__ __launch_bounds__(256) void gemm_l0(const float* __restrict__ Xin,
                                               const float* __restrict__ W,
                                               const float* __restrict__ dinv,
                                               unsigned short* __restrict__ Gb) {
    __shared__ s16x8 WL[8][64];   // [t*2+c][lane], 8KB
    int lane = threadIdx.x & 63;
    int n16 = lane & 15, quad = lane >> 4;

#pragma unroll
    for (int e = threadIdx.x; e < 512; e += 256) {
        int ln = e & 63, tc = e >> 6;
        int tt = tc >> 1, cc = tc & 1;
        int m16 = ln & 15, qq = ln >> 4;
        const float4* wp = (const float4*)(W + (tt * 16 + m16) * 64 + cc * 32 + qq * 8);
        float4 w0 = wp[0], w1 = wp[1];
        s16x8 f;
        f[0] = f2b(w0.x); f[1] = f2b(w0.y); f[2] = f2b(w0.z); f[3] = f2b(w0.w);
        f[4] = f2b(w1.x); f[5] = f2b(w1.y); f[6] = f2b(w1.z); f[7] = f2b(w1.w);
        WL[tc][ln] = f;
    }
    __syncthreads();

    s16x8 bfrag[4][2];
#pragma unroll
    for (int t = 0; t < 4; ++t)
#pragma unroll
        for (int c = 0; c < 2; ++c)
            bfrag[t][c] = WL[t * 2 + c][lane];

    int wid = (blockIdx.x * blockDim.x + threadIdx.x) >> 6;
    int nw  = (gridDim.x * blockDim.x) >> 6;
    for (int tile = wid; tile < NN / 16; tile += nw) {
        int r0 = tile * 16;
        int m  = r0 + n16;
        s16x8 a[2];
#pragma unroll
        for (int c = 0; c < 2; ++c) {
            const float4* xp = (const float4*)(Xin + (size_t)m * 64 + c * 32 + quad * 8);
            float4 x0 = xp[0], x1 = xp[1];
            s16x8 f;
            f[0] = f2b(x0.x); f[1] = f2b(x0.y); f[2] = f2b(x0.z); f[3] = f2b(x0.w);
            f[4] = f2b(x1.x); f[5] = f2b(x1.y); f[6] = f2b(x1.z); f[7] = f2b(x1.w);
            a[c] = f;
        }
        f32x4 acc[4] = {{0,0,0,0},{0,0,0,0},{0,0,0,0},{0,0,0,0}};
#pragma unroll
        for (int c = 0; c < 2; ++c)
#pragma unroll
            for (int t = 0; t < 4; ++t)
                acc[t] = __builtin_amdgcn_mfma_f32_16x16x32_bf16(a[c], bfrag[t][c], acc[t], 0, 0, 0);

        float dvr[4];
#pragma unroll
        for (int r = 0; r < 4; ++r) dvr[r] = dinv[r0 + quad * 4 + r];
#pragma unroll
        for (int t = 0; t < 4; ++t)
#pragma unroll
            for (int r = 0; r < 4; ++r)
                Gb[(size_t)(r0 + quad * 4 + r) * 64 + t * 16 + n16] =
                    (unsigned short)f2b(dvr[r] * acc[t][r]);
    }
}

// ---------------------------------------------------------------------------
// 8-neighbor accumulation batch for one 16-lane group (unchanged).
template <int BASE>
__device__ __forceinline__ void gbatch8(const unsigned short* __restrict__ Gb,
                                        int v, int c, int g, int n, int ir,
                                        float& ax, float& ay, float& az, float& aw) {
    ushort4 val[8];
    float msk[8];
#pragma unroll
    for (int u = 0; u < 8; ++u) {
        int j = BASE + u;
        int s = __shfl(ir, g * 16 + (j & 15), 64);
        bool ok = j < n;
        msk[u] = ok ? 1.0f : 0.0f;
        val[u] = *(const ushort4*)(Gb + (size_t)(ok ? s : v) * 64 + c * 4);
    }
#pragma unroll
    for (int u = 0; u < 8; ++u) {
        ax = fmaf(msk[u], b2f(val[u].x), ax);
        ay = fmaf(msk[u], b2f(val[u].y), ay);
        az = fmaf(msk[u], b2f(val[u].z), az);
        aw = fmaf(msk[u], b2f(val[u].w), aw);
    }
}

// ---------------------------------------------------------------------------
// Fused gather (r15 verified, -14us). Block = 4 waves x 4 rows = one tile.
// FUSE=1: next-layer transform in wave 0. FUSE=0: plain gather for BN.
template <int FUSE>
__global__ __launch_bounds__(256) void gather_fused(const int* __restrict__ cursor,
                                                    const int* __restrict__ csr_src,
                                                    const unsigned short* __restrict__ Gb_in,
                                                    const float* __restrict__ W,
                                                    const float* __restrict__ dinv,
                                                    const float* __restrict__ c0,
                                                    unsigned short* __restrict__ outp) {
    __shared__ s16x8 WL[8][64];    // next-layer W frags, 8KB (FUSE only)
    __shared__ float AT[16][68];   // aggregated tile, f32, +4 pad
    int lane = threadIdx.x & 63, wave = threadIdx.x >> 6;
    int c = lane & 15, g = lane >> 4;

    if (FUSE) {
#pragma unroll
        for (int e = threadIdx.x; e < 512; e += 256) {
            int ln = e & 63, tc = e >> 6;
            int tt = tc >> 1, cc2 = tc & 1;
            int m16 = ln & 15, qq = ln >> 4;
            const float4* wp = (const float4*)(W + (tt * 16 + m16) * 64 + cc2 * 32 + qq * 8);
            float4 w0 = wp[0], w1 = wp[1];
            s16x8 f;
            f[0] = f2b(w0.x); f[1] = f2b(w0.y); f[2] = f2b(w0.z); f[3] = f2b(w0.w);
            f[4] = f2b(w1.x); f[5] = f2b(w1.y); f[6] = f2b(w1.z); f[7] = f2b(w1.w);
            WL[tc][ln] = f;
        }
    }

    int r0 = blockIdx.x * 16;              // NN/16 = 6250 blocks exactly
    int v  = r0 + wave * 4 + g;
    int n = cursor[v * CPAD]; if (n > SLOT) n = SLOT;
    int i0 = csr_src[v * SLOT + c];
    ushort4 sv = *(const ushort4*)(Gb_in + (size_t)v * 64 + c * 4);
    float ax = b2f(sv.x), ay = b2f(sv.y), az = b2f(sv.z), aw = b2f(sv.w);
    if (n > 0)  gbatch8<0 >(Gb_in, v, c, g, n, i0, ax, ay, az, aw);
    if (n > 8)  gbatch8<8 >(Gb_in, v, c, g, n, i0, ax, ay, az, aw);
    if (n > 16) {
        int i1 = csr_src[v * SLOT + 16 + c];
        gbatch8<16>(Gb_in, v, c, g, n, i1, ax, ay, az, aw);
        if (n > 24) gbatch8<24>(Gb_in, v, c, g, n, i1, ax, ay, az, aw);
        if (n > 32) {
            int i2 = csr_src[v * SLOT + 32 + (c & 7)];
            gbatch8<32>(Gb_in, v, c, g, n, i2, ax, ay, az, aw);
        }
    }

    if (!FUSE) {
        ushort4 o;
        o.x = (unsigned short)f2b(ax); o.y = (unsigned short)f2b(ay);
        o.z = (unsigned short)f2b(az); o.w = (unsigned short)f2b(aw);
        *(ushort4*)(outp + (size_t)v * 64 + c * 4) = o;
        return;
    }

    float4 f4; f4.x = ax; f4.y = ay; f4.z = az; f4.w = aw;
    *(float4*)&AT[wave * 4 + g][c * 4] = f4;
    __syncthreads();
    if (wave != 0) return;

    // --- wave 0: transform the 16-row tile (next layer) ---
    int n16 = lane & 15, quad = lane >> 4;
    s16x8 a[2];
#pragma unroll
    for (int cc2 = 0; cc2 < 2; ++cc2) {
        const float* ap = &AT[n16][cc2 * 32 + quad * 8];
        s16x8 f;
#pragma unroll
        for (int q2 = 0; q2 < 8; ++q2) f[q2] = f2b(ap[q2]);
        a[cc2] = f;
    }
    s16x8 bfrag[4][2];
#pragma unroll
    for (int t = 0; t < 4; ++t)
#pragma unroll
        for (int cc2 = 0; cc2 < 2; ++cc2)
            bfrag[t][cc2] = WL[t * 2 + cc2][lane];

    f32x4 acc[4] = {{0,0,0,0},{0,0,0,0},{0,0,0,0},{0,0,0,0}};
#pragma unroll
    for (int cc2 = 0; cc2 < 2; ++cc2)
#pragma unroll
        for (int t = 0; t < 4; ++t)
            acc[t] = __builtin_amdgcn_mfma_f32_16x16x32_bf16(a[cc2], bfrag[t][cc2], acc[t], 0, 0, 0);

    float dvr[4];
#pragma unroll
    for (int r = 0; r < 4; ++r) dvr[r] = dinv[r0 + quad * 4 + r];
#pragma unroll
    for (int t = 0; t < 4; ++t) {
        float cc2 = c0[t * 16 + n16];
#pragma unroll
        for (int r = 0; r < 4; ++r) {
            float dv = dvr[r];
            float g2 = dv * dv * acc[t][r] + dv * cc2;
            outp[(size_t)(r0 + quad * 4 + r) * 64 + t * 16 + n16] = (unsigned short)f2b(g2);
        }
    }
}

// ---------------------------------------------------------------------------
__global__ __launch_bounds__(256) void bn_stats(const unsigned short* __restrict__ ACCb,
                                                const float* __restrict__ dinv,
                                                const float* __restrict__ blast,
                                                float* __restrict__ sums) {
    int j = threadIdx.x & 63;
    float b = blast[j];
    int wid = (blockIdx.x * blockDim.x + threadIdx.x) >> 6;
    int nw  = (gridDim.x * blockDim.x) >> 6;
    float s = 0.0f, s2 = 0.0f;
    for (int v = wid; v < NN; v += nw) {
        float y = dinv[v] * b2f(ACCb[(size_t)v * 64 + j]) + b;
        s += y;
        s2 += y * y;
    }
    __shared__ float ls[256], ls2[256];
    ls[threadIdx.x] = s;
    ls2[threadIdx.x] = s2;
    __syncthreads();
    if (threadIdx.x < 64) {
        s  = ls[threadIdx.x] + ls[threadIdx.x + 64] + ls[threadIdx.x + 128] + ls[threadIdx.x + 192];
        s2 = ls2[threadIdx.x] + ls2[threadIdx.x + 64] + ls2[threadIdx.x + 128] + ls2[threadIdx.x + 192];
        atomicAdd(&sums[j], s);
        atomicAdd(&sums[64 + j], s2);
    }
}

__global__ __launch_bounds__(256) void bn_apply(const unsigned short* __restrict__ ACCb,
                                                const float* __restrict__ dinv,
                                                const float* __restrict__ blast,
                                                const float* __restrict__ sums,
                                                const float* __restrict__ gamma,
                                                const float* __restrict__ beta,
                                                float* __restrict__ out) {
    const float invN = 1.0f / (float)NN;
    int stride = gridDim.x * blockDim.x;
    for (int i = blockIdx.x * blockDim.x + threadIdx.x; i < NN * 64; i += stride) {
        int j = i & 63;
        int v = i >> 6;
        float mean = sums[j] * invN;
        float var  = sums[64 + j] * invN - mean * mean;
        float y = dinv[v] * b2f(ACCb[i]) + blast[j];
        out[i] = (y - mean) * rsqrtf(var + BN_EPS) * gamma[j] + beta[j];
    }
}

// ---------------------------------------------------------------------------
extern "C" void kernel_launch(void* const* d_in, const int* in_sizes, int n_in,
                              void* d_out, int out_size, void* d_ws, size_t ws_size,
                              hipStream_t stream) {
    const float* x     = (const float*)d_in[0];
    const int*   ei    = (const int*)d_in[1];
    const float* Ws    = (const float*)d_in[2];
    const float* bs    = (const float*)d_in[3];
    const float* gamma = (const float*)d_in[4];
    const float* beta  = (const float*)d_in[5];
    float* out = (float*)d_out;

    char* ws = (char*)d_ws;
    size_t off = 0;
    unsigned short* ACCb = (unsigned short*)(ws + off); off += (size_t)NN * 64 * 2;
    unsigned short* GbA  = (unsigned short*)(ws + off); off += (size_t)NN * 64 * 2;
    unsigned short* GbB  = (unsigned short*)(ws + off); off += (size_t)NN * 64 * 2;
    float* dinv    = (float*)(ws + off); off += (size_t)NN * 4;
    float* sums    = (float*)(ws + off); off += 128 * 4;
    float* c0      = (float*)(ws + off); off += 128 * 4;
    int*   cursor  = (int*)(ws + off);   off += (size_t)NN * CPAD * 4;
    int*   csr_src = (int*)(ws + off);   off += (size_t)NN * SLOT * 4;

    hipMemsetAsync(cursor, 0, (size_t)NN * CPAD * sizeof(int), stream);
    hipMemsetAsync(sums, 0, 128 * sizeof(float), stream);

    // --- slot-CSR build: bucketed, plain cached loads ---
    place_part<<<NBUCK * NCHUNK, 256, 0, stream>>>(ei, cursor, csr_src);
    dinv_c0<<<(NN + 255) / 256, 256, 0, stream>>>(cursor, dinv, Ws, bs, c0);

    // --- 3 GCN layers: L0 transform, fused gather+transform, last plain ---
    gemm_l0<<<1563, 256, 0, stream>>>(x, Ws, dinv, GbA);
    gather_fused<1><<<6250, 256, 0, stream>>>(cursor, csr_src, GbA,
                                              Ws + 4096, dinv, c0, GbB);
    gather_fused<1><<<6250, 256, 0, stream>>>(cursor, csr_src, GbB,
                                              Ws + 8192, dinv, c0 + 64, GbA);
    gather_fused<0><<<6250, 256, 0, stream>>>(cursor, csr_src, GbA,
                                              nullptr, nullptr, nullptr, ACCb);

    // --- BatchNorm ---
    bn_stats<<<2048, 256, 0, stream>>>(ACCb, dinv, bs + 128, sums);
    bn_apply<<<2048, 256, 0, stream>>>(ACCb, dinv, bs + 128, sums, gamma, beta, out);
}